// Round 13
// baseline (235.618 us; speedup 1.0000x reference)
//
#include <hip/hip_runtime.h>

#define N_NODES 40000
#define N_EDGES 640000
#define HD 128
#define N_REL2 474
#define NRP 480  // padded relation count
#define BN_EPS 1e-5f

typedef _Float16 half8 __attribute__((ext_vector_type(8)));
typedef float f32x4 __attribute__((ext_vector_type(4)));

// K1: per-(node, rel) edge-count histogram, nibble-packed (480 nibbles = 60 u32/row)
__global__ __launch_bounds__(256) void k_cnt(
        const int* __restrict__ dst, const int* __restrict__ rel_id,
        unsigned* __restrict__ cnt4) {
    int e = blockIdx.x * 256 + threadIdx.x;
    if (e < N_EDGES) {
        int d = dst[e], r = rel_id[e];
        atomicAdd(&cnt4[d * 60 + (r >> 3)], 1u << (4 * (r & 7)));
    }
}

// K2: per-rel row: R_hl = fp16 hi|lo of rel_emb ([480][256] halfs, pad zeroed);
//     RWT = (rel_emb @ neigh_w)^T as fp16 hi|lo ([128 cols][960]: hi 480 | lo 480)
__global__ __launch_bounds__(128) void k_rw(
        const float* __restrict__ R, const float* __restrict__ W,
        _Float16* __restrict__ R_hl, _Float16* __restrict__ RWT) {
    __shared__ float row[HD];
    int r = blockIdx.x, c = threadIdx.x;
    float rv = R[(size_t)r * HD + c];
    row[c] = rv;
    _Float16 hh = (_Float16)rv;
    R_hl[r * 256 + c] = hh;
    R_hl[r * 256 + 128 + c] = (_Float16)(rv - (float)hh);
    __syncthreads();
    float acc = 0.f;
    #pragma unroll 8
    for (int k = 0; k < HD; ++k) acc += row[k] * W[(size_t)k * HD + c];
    _Float16 ah = (_Float16)acc;
    RWT[c * 960 + r] = ah;
    RWT[c * 960 + 480 + r] = (_Float16)(acc - (float)ah);
}

// K3 (mega): per block of 32 nodes:
//   GEMM1: G(32x480) = ent(32x128) @ R^T   [fp16 hi/lo 3-term MFMA, in regs]
//   masked row-max over present rels -> p = exp(G-m), A = cnt*p (fp16, LDS), l = rowsum
//   GEMM2: h(32x128) = A @ RW              [RW fp16 hi/lo 2-term MFMA]
__global__ __launch_bounds__(256) void k_mega(
        const float* __restrict__ ent, const _Float16* __restrict__ R_hl,
        const _Float16* __restrict__ RWT, const unsigned* __restrict__ cnt4,
        float* __restrict__ h) {
    __shared__ _Float16 As[32 * 488];       // A tile, row stride 488 (bank-spread)
    __shared__ unsigned char cntb[32 * 480];
    __shared__ float maxp[4 * 32];
    __shared__ float sump[4 * 32];
    __shared__ float m_s[32];
    __shared__ float l_s[32];

    int t = threadIdx.x, w = t >> 6, l = t & 63;
    int nb = blockIdx.x;
    int lr = l & 15;   // A-row / B-col / D-col
    int lk = l >> 4;   // k-group / D-row-group

    // stage cnt nibbles -> bytes in LDS (coalesced global, packed LDS writes)
    for (int i = t; i < 1920; i += 256) {
        unsigned wv = cnt4[nb * 1920 + i];
        unsigned lo4 = (wv & 0xFu) | (((wv >> 4) & 0xFu) << 8) |
                       (((wv >> 8) & 0xFu) << 16) | (((wv >> 12) & 0xFu) << 24);
        unsigned hi4 = ((wv >> 16) & 0xFu) | (((wv >> 20) & 0xFu) << 8) |
                       (((wv >> 24) & 0xFu) << 16) | (((wv >> 28) & 0xFu) << 24);
        ((unsigned*)cntb)[i * 2] = lo4;
        ((unsigned*)cntb)[i * 2 + 1] = hi4;
    }

    // ---- GEMM1: acc[rt][ci] covers rows rt*16+lk*4+reg, cols (w+ci*4)*16+lr ----
    f32x4 acc[2][8];
    #pragma unroll
    for (int rt = 0; rt < 2; ++rt)
        #pragma unroll
        for (int ci = 0; ci < 8; ++ci)
            acc[rt][ci] = (f32x4){0.f, 0.f, 0.f, 0.f};

    for (int kf = 0; kf < 4; ++kf) {
        half8 ah[2], al[2];
        #pragma unroll
        for (int rt = 0; rt < 2; ++rt) {
            const float* ep = ent + ((size_t)(nb * 32 + rt * 16 + lr)) * HD + kf * 32 + lk * 8;
            float4 v0 = *(const float4*)ep;
            float4 v1 = *(const float4*)(ep + 4);
            float vv[8] = {v0.x, v0.y, v0.z, v0.w, v1.x, v1.y, v1.z, v1.w};
            #pragma unroll
            for (int j = 0; j < 8; ++j) {
                _Float16 hh = (_Float16)vv[j];
                ah[rt][j] = hh;
                al[rt][j] = (_Float16)(vv[j] - (float)hh);
            }
        }
        #pragma unroll
        for (int ci = 0; ci < 8; ++ci) {
            int ct = w + ci * 4;
            if (ct < 30) {
                const _Float16* bp = R_hl + (ct * 16 + lr) * 256 + kf * 32 + lk * 8;
                half8 bh = *(const half8*)bp;
                half8 bl = *(const half8*)(bp + 128);
                #pragma unroll
                for (int rt = 0; rt < 2; ++rt) {
                    acc[rt][ci] = __builtin_amdgcn_mfma_f32_16x16x32_f16(al[rt], bh, acc[rt][ci], 0, 0, 0);
                    acc[rt][ci] = __builtin_amdgcn_mfma_f32_16x16x32_f16(ah[rt], bl, acc[rt][ci], 0, 0, 0);
                    acc[rt][ci] = __builtin_amdgcn_mfma_f32_16x16x32_f16(ah[rt], bh, acc[rt][ci], 0, 0, 0);
                }
            }
        }
    }
    __syncthreads();  // cntb ready

    // ---- masked row max (present rels only) ----
    #pragma unroll
    for (int rt = 0; rt < 2; ++rt) {
        #pragma unroll
        for (int reg = 0; reg < 4; ++reg) {
            int row = rt * 16 + lk * 4 + reg;
            float m = -INFINITY;
            #pragma unroll
            for (int ci = 0; ci < 8; ++ci) {
                int ct = w + ci * 4;
                if (ct < 30) {
                    int col = ct * 16 + lr;
                    if (cntb[row * 480 + col]) m = fmaxf(m, acc[rt][ci][reg]);
                }
            }
            #pragma unroll
            for (int msk = 1; msk <= 8; msk <<= 1)
                m = fmaxf(m, __shfl_xor(m, msk, 64));
            if (lr == 0) maxp[w * 32 + row] = m;
        }
    }
    __syncthreads();
    if (t < 32) m_s[t] = fmaxf(fmaxf(maxp[t], maxp[32 + t]), fmaxf(maxp[64 + t], maxp[96 + t]));
    __syncthreads();

    // ---- A = cnt * exp(G - m) (fp16 -> LDS), partial row sums ----
    #pragma unroll
    for (int rt = 0; rt < 2; ++rt) {
        #pragma unroll
        for (int reg = 0; reg < 4; ++reg) {
            int row = rt * 16 + lk * 4 + reg;
            float m = m_s[row];
            float ps = 0.f;
            #pragma unroll
            for (int ci = 0; ci < 8; ++ci) {
                int ct = w + ci * 4;
                if (ct < 30) {
                    int col = ct * 16 + lr;
                    float p = fminf(__expf(acc[rt][ci][reg] - m), 30000.f);
                    float a = (float)cntb[row * 480 + col] * p;
                    ps += a;
                    As[row * 488 + col] = (_Float16)a;
                }
            }
            #pragma unroll
            for (int msk = 1; msk <= 8; msk <<= 1)
                ps += __shfl_xor(ps, msk, 64);
            if (lr == 0) sump[w * 32 + row] = ps;
        }
    }
    __syncthreads();
    if (t < 32) l_s[t] = sump[t] + sump[32 + t] + sump[64 + t] + sump[96 + t];
    __syncthreads();

    // ---- GEMM2: h = A(32x480) @ RW(480x128); wave: rt2 = w>>1, cols (w&1)*64.. ----
    int rt2 = w >> 1, ctp = (w & 1) * 4;
    f32x4 a2[4];
    #pragma unroll
    for (int ci = 0; ci < 4; ++ci) a2[ci] = (f32x4){0.f, 0.f, 0.f, 0.f};
    for (int kf = 0; kf < 15; ++kf) {
        half8 af = *(const half8*)&As[(rt2 * 16 + lr) * 488 + kf * 32 + lk * 8];
        #pragma unroll
        for (int ci = 0; ci < 4; ++ci) {
            int col2 = (ctp + ci) * 16 + lr;
            const _Float16* bp = RWT + col2 * 960 + kf * 32 + lk * 8;
            half8 bh = *(const half8*)bp;
            half8 bl = *(const half8*)(bp + 480);
            a2[ci] = __builtin_amdgcn_mfma_f32_16x16x32_f16(af, bh, a2[ci], 0, 0, 0);
            a2[ci] = __builtin_amdgcn_mfma_f32_16x16x32_f16(af, bl, a2[ci], 0, 0, 0);
        }
    }
    float invl[4];
    #pragma unroll
    for (int reg = 0; reg < 4; ++reg) {
        float lv = l_s[rt2 * 16 + lk * 4 + reg];
        invl[reg] = (lv > 0.f) ? 1.f / lv : 0.f;
    }
    #pragma unroll
    for (int ci = 0; ci < 4; ++ci) {
        #pragma unroll
        for (int reg = 0; reg < 4; ++reg) {
            int row = rt2 * 16 + lk * 4 + reg;
            h[((size_t)nb * 32 + row) * HD + (ctp + ci) * 16 + lr] = a2[ci][reg] * invl[reg];
        }
    }
}

// K4: per-column sum / sumsq over rows (block-partial -> global atomics)
__global__ __launch_bounds__(256) void k_stats(
        const float* __restrict__ Hout, float* __restrict__ colsum,
        float* __restrict__ colsumsq) {
    __shared__ float ls[256], lq[256];
    int t = threadIdx.x;
    int c = t & 127, half = t >> 7;
    int rbase = blockIdx.x * 64;
    float sum = 0.f, sq = 0.f;
    #pragma unroll 4
    for (int i = 0; i < 32; ++i) {
        int r = rbase + half + i * 2;
        float v = Hout[(size_t)r * HD + c];
        sum += v;
        sq += v * v;
    }
    ls[t] = sum;
    lq[t] = sq;
    __syncthreads();
    if (t < 128) {
        sum = ls[t] + ls[t + 128];
        sq = lq[t] + lq[t + 128];
        atomicAdd(colsum + c, sum);
        atomicAdd(colsumsq + c, sq);
    }
}

// K5: out = tanh((h - mean) * rstd * gamma + beta), in place; fast tanh
__global__ __launch_bounds__(256) void k_apply(
        float* __restrict__ Hout, const float* __restrict__ colsum,
        const float* __restrict__ colsumsq, const float* __restrict__ gamma,
        const float* __restrict__ beta) {
    int idx = blockIdx.x * 256 + threadIdx.x;  // float4 index
    if (idx >= N_NODES * HD / 4) return;
    int c0 = (idx * 4) & 127;
    float4 hv4 = ((const float4*)Hout)[idx];
    const float inv = 1.f / (float)N_NODES;
    float hv[4] = {hv4.x, hv4.y, hv4.z, hv4.w};
    float o[4];
    #pragma unroll
    for (int j = 0; j < 4; ++j) {
        int c = c0 + j;
        float mean = colsum[c] * inv;
        float var = colsumsq[c] * inv - mean * mean;
        float rstd = rsqrtf(var + BN_EPS);
        float x = (hv[j] - mean) * rstd * gamma[c] + beta[c];
        o[j] = 1.f - 2.f / (__expf(2.f * x) + 1.f);
    }
    ((float4*)Hout)[idx] = make_float4(o[0], o[1], o[2], o[3]);
}

extern "C" void kernel_launch(void* const* d_in, const int* in_sizes, int n_in,
                              void* d_out, int out_size, void* d_ws, size_t ws_size,
                              hipStream_t stream) {
    const float* ent_emb  = (const float*)d_in[0];
    const float* rel_emb  = (const float*)d_in[1];
    const float* neigh_w  = (const float*)d_in[2];
    const float* bn_gamma = (const float*)d_in[3];
    const float* bn_beta  = (const float*)d_in[4];
    const int*   rel_id   = (const int*)d_in[5];
    const int*   dst      = (const int*)d_in[6];
    float* out = (float*)d_out;

    // workspace layout (4-byte words) — ALL of it memset to 0 each call
    unsigned* cnt4   = (unsigned*)d_ws;                       // [40000*60] nibble counts
    float*    colsum = (float*)d_ws + 2400000;                // [128]
    float*    colsumsq = colsum + 128;                        // [128]
    _Float16* R_hl   = (_Float16*)((float*)d_ws + 2400256);   // [480*256] halfs (pad 0)
    _Float16* RWT    = (_Float16*)((float*)d_ws + 2461696);   // [128*960] halfs (pad 0)
    // total words = 2,523,136  (≈10.1 MB)

    hipMemsetAsync(d_ws, 0, (size_t)2523136 * 4, stream);

    k_cnt<<<(N_EDGES + 255) / 256, 256, 0, stream>>>(dst, rel_id, cnt4);
    k_rw<<<N_REL2, 128, 0, stream>>>(rel_emb, neigh_w, R_hl, RWT);
    k_mega<<<N_NODES / 32, 256, 0, stream>>>(ent_emb, R_hl, RWT, cnt4, out);
    k_stats<<<N_NODES / 64, 256, 0, stream>>>(out, colsum, colsumsq);
    k_apply<<<N_NODES * HD / 4 / 256, 256, 0, stream>>>(out, colsum, colsumsq, bn_gamma, bn_beta);
}

// Round 14
// 224.217 us; speedup vs baseline: 1.0509x; 1.0509x over previous
//
#include <hip/hip_runtime.h>

#define N_NODES 40000
#define N_EDGES 640000
#define HD 128
#define N_REL2 474
#define BN_EPS 1e-5f

typedef _Float16 half8 __attribute__((ext_vector_type(8)));
typedef float f32x4 __attribute__((ext_vector_type(4)));

// K1: per-(node, rel) edge-count histogram, nibble-packed (480 nibbles = 60 u32/row)
__global__ __launch_bounds__(256) void k_cnt(
        const int* __restrict__ dst, const int* __restrict__ rel_id,
        unsigned* __restrict__ cnt4) {
    int e = blockIdx.x * 256 + threadIdx.x;
    if (e < N_EDGES) {
        int d = dst[e], r = rel_id[e];
        atomicAdd(&cnt4[d * 60 + (r >> 3)], 1u << (4 * (r & 7)));
    }
}

// K2: R_hl = fp16 hi|lo of rel_emb ([480][256] halfs, pad rows zeroed);
//     RWT = (rel_emb @ neigh_w)^T fp16 hi|lo ([128 cols][960]: hi 480 | lo 480)
__global__ __launch_bounds__(128) void k_rw(
        const float* __restrict__ R, const float* __restrict__ W,
        _Float16* __restrict__ R_hl, _Float16* __restrict__ RWT) {
    __shared__ float row[HD];
    int r = blockIdx.x, c = threadIdx.x;
    float rv = (r < N_REL2) ? R[(size_t)r * HD + c] : 0.f;
    row[c] = rv;
    _Float16 hh = (_Float16)rv;
    R_hl[r * 256 + c] = hh;
    R_hl[r * 256 + 128 + c] = (_Float16)(rv - (float)hh);
    __syncthreads();
    float acc = 0.f;
    #pragma unroll 8
    for (int k = 0; k < HD; ++k) acc += row[k] * W[(size_t)k * HD + c];
    _Float16 ah = (_Float16)acc;
    RWT[c * 960 + r] = ah;
    RWT[c * 960 + 480 + r] = (_Float16)(acc - (float)ah);
}

// K3 (mega v2): per 32-node block, LDS-staged B operands for both GEMMs.
//   GEMM1: G(32x480) = ent @ R^T (fp16 hi/lo 3-term MFMA, B staged per slice)
//   masked row-max -> A = cnt*exp(G-m) (fp16, LDS), l = rowsum
//   GEMM2: h = A @ RW (RWT staged per K-step), scaled by 1/l
__global__ __launch_bounds__(256) void k_mega(
        const float* __restrict__ ent, const _Float16* __restrict__ R_hl,
        const _Float16* __restrict__ RWT, const unsigned* __restrict__ cnt4,
        float* __restrict__ h) {
    __shared__ __align__(16) unsigned char lds[52992];
    _Float16* Bs  = (_Float16*)lds;               // [2][160][40] (GEMM1 slice)
    _Float16* As  = (_Float16*)lds;               // [32][488]  (union w/ Bs)
    unsigned* cnb = (unsigned*)(lds + 31232);     // [32][61]
    _Float16* Bs2 = (_Float16*)(lds + 31232);     // [2][128][40] (union w/ cnb)
    float* maxp = (float*)(lds + 51712);          // [4][32]
    float* sump = maxp + 128;                     // [4][32]
    float* m_s  = sump + 128;                     // [32]
    float* l_s  = m_s + 32;                       // [32]

    int t = threadIdx.x, w = t >> 6, l = t & 63;
    int nb = blockIdx.x;
    int lr = l & 15;   // A-row / B-col / D-col
    int lk = l >> 4;   // k-group / D-row-group

    // stage cnt nibbles into padded u32 array
    for (int i = t; i < 1920; i += 256) {
        int row = i / 60, ww = i - row * 60;
        cnb[row * 61 + ww] = cnt4[(size_t)(nb * 32 + row) * 60 + ww];
    }

    f32x4 acc[2][9];
    #pragma unroll
    for (int rt = 0; rt < 2; ++rt)
        #pragma unroll
        for (int ai = 0; ai < 9; ++ai)
            acc[rt][ai] = (f32x4){0.f, 0.f, 0.f, 0.f};

    // ---- GEMM1: 4 kf slices x 3 row-thirds, B from LDS ----
    for (int kf = 0; kf < 4; ++kf) {
        half8 ah[2], al[2];
        #pragma unroll
        for (int rt = 0; rt < 2; ++rt) {
            const float* ep = ent + ((size_t)(nb * 32 + rt * 16 + lr)) * HD + kf * 32 + lk * 8;
            float4 v0 = *(const float4*)ep;
            float4 v1 = *(const float4*)(ep + 4);
            float vv[8] = {v0.x, v0.y, v0.z, v0.w, v1.x, v1.y, v1.z, v1.w};
            #pragma unroll
            for (int j = 0; j < 8; ++j) {
                _Float16 hh = (_Float16)vv[j];
                ah[rt][j] = hh;
                al[rt][j] = (_Float16)(vv[j] - (float)hh);
            }
        }
        for (int third = 0; third < 3; ++third) {
            for (int i = t; i < 1280; i += 256) {
                int plane = i / 640, j = i - plane * 640;
                int row = j >> 2, seg = j & 3;
                *(float4*)(Bs + plane * 6400 + row * 40 + seg * 8) =
                    *(const float4*)(R_hl + (size_t)(third * 160 + row) * 256 + plane * 128 + kf * 32 + seg * 8);
            }
            __syncthreads();
            #pragma unroll
            for (int ci = 0; ci < 3; ++ci) {
                int lt = w + ci * 4;
                if (lt < 10) {
                    const _Float16* bp = Bs + (lt * 16 + lr) * 40 + lk * 8;
                    half8 bh = *(const half8*)bp;
                    half8 bl = *(const half8*)(bp + 6400);
                    int ai = third * 3 + ci;
                    #pragma unroll
                    for (int rt = 0; rt < 2; ++rt) {
                        acc[rt][ai] = __builtin_amdgcn_mfma_f32_16x16x32_f16(al[rt], bh, acc[rt][ai], 0, 0, 0);
                        acc[rt][ai] = __builtin_amdgcn_mfma_f32_16x16x32_f16(ah[rt], bl, acc[rt][ai], 0, 0, 0);
                        acc[rt][ai] = __builtin_amdgcn_mfma_f32_16x16x32_f16(ah[rt], bh, acc[rt][ai], 0, 0, 0);
                    }
                }
            }
            __syncthreads();
        }
    }

    // ---- masked row max (present rels only) ----
    #pragma unroll
    for (int rt = 0; rt < 2; ++rt) {
        #pragma unroll
        for (int reg = 0; reg < 4; ++reg) {
            int row = rt * 16 + lk * 4 + reg;
            float m = -INFINITY;
            #pragma unroll
            for (int third = 0; third < 3; ++third)
                #pragma unroll
                for (int ci = 0; ci < 3; ++ci) {
                    int lt = w + ci * 4;
                    if (lt < 10) {
                        int col = (third * 10 + lt) * 16 + lr;
                        unsigned nib = (cnb[row * 61 + (col >> 3)] >> ((col & 7) * 4)) & 15u;
                        if (nib) m = fmaxf(m, acc[rt][third * 3 + ci][reg]);
                    }
                }
            #pragma unroll
            for (int msk = 1; msk <= 8; msk <<= 1)
                m = fmaxf(m, __shfl_xor(m, msk, 64));
            if (lr == 0) maxp[w * 32 + row] = m;
        }
    }
    __syncthreads();
    if (t < 32) m_s[t] = fmaxf(fmaxf(maxp[t], maxp[32 + t]), fmaxf(maxp[64 + t], maxp[96 + t]));
    __syncthreads();

    // ---- A = cnt * exp(G - m) -> fp16 LDS, partial row sums ----
    #pragma unroll
    for (int rt = 0; rt < 2; ++rt) {
        #pragma unroll
        for (int reg = 0; reg < 4; ++reg) {
            int row = rt * 16 + lk * 4 + reg;
            float m = m_s[row];
            float ps = 0.f;
            #pragma unroll
            for (int third = 0; third < 3; ++third)
                #pragma unroll
                for (int ci = 0; ci < 3; ++ci) {
                    int lt = w + ci * 4;
                    if (lt < 10) {
                        int col = (third * 10 + lt) * 16 + lr;
                        unsigned nib = (cnb[row * 61 + (col >> 3)] >> ((col & 7) * 4)) & 15u;
                        float p = fminf(__expf(acc[rt][third * 3 + ci][reg] - m), 30000.f);
                        float a = (float)nib * p;
                        ps += a;
                        As[row * 488 + col] = (_Float16)a;
                    }
                }
            #pragma unroll
            for (int msk = 1; msk <= 8; msk <<= 1)
                ps += __shfl_xor(ps, msk, 64);
            if (lr == 0) sump[w * 32 + row] = ps;
        }
    }
    __syncthreads();
    if (t < 32) l_s[t] = sump[t] + sump[32 + t] + sump[64 + t] + sump[96 + t];
    __syncthreads();

    // ---- GEMM2: h = A @ RW, B (RWT) staged per K-step ----
    int rt2 = w >> 1, ctp = (w & 1) * 4;
    f32x4 a2[4];
    #pragma unroll
    for (int ci = 0; ci < 4; ++ci) a2[ci] = (f32x4){0.f, 0.f, 0.f, 0.f};
    for (int kf2 = 0; kf2 < 15; ++kf2) {
        for (int i = t; i < 1024; i += 256) {
            int plane = i >> 9, j = i & 511;
            int col = j >> 2, seg = j & 3;
            *(float4*)(Bs2 + plane * 5120 + col * 40 + seg * 8) =
                *(const float4*)(RWT + (size_t)col * 960 + plane * 480 + kf2 * 32 + seg * 8);
        }
        __syncthreads();
        half8 af = *(const half8*)(As + (rt2 * 16 + lr) * 488 + kf2 * 32 + lk * 8);
        #pragma unroll
        for (int ci = 0; ci < 4; ++ci) {
            int col2 = (ctp + ci) * 16 + lr;
            const _Float16* bp = Bs2 + col2 * 40 + lk * 8;
            half8 bh = *(const half8*)bp;
            half8 bl = *(const half8*)(bp + 5120);
            a2[ci] = __builtin_amdgcn_mfma_f32_16x16x32_f16(af, bh, a2[ci], 0, 0, 0);
            a2[ci] = __builtin_amdgcn_mfma_f32_16x16x32_f16(af, bl, a2[ci], 0, 0, 0);
        }
        __syncthreads();
    }

    float invl[4];
    #pragma unroll
    for (int reg = 0; reg < 4; ++reg) {
        float lv = l_s[rt2 * 16 + lk * 4 + reg];
        invl[reg] = (lv > 0.f) ? 1.f / lv : 0.f;
    }
    #pragma unroll
    for (int ci = 0; ci < 4; ++ci) {
        #pragma unroll
        for (int reg = 0; reg < 4; ++reg) {
            int row = rt2 * 16 + lk * 4 + reg;
            h[((size_t)nb * 32 + row) * HD + (ctp + ci) * 16 + lr] = a2[ci][reg] * invl[reg];
        }
    }
}

// K4: per-column sum / sumsq over rows (block-partial -> global atomics)
__global__ __launch_bounds__(256) void k_stats(
        const float* __restrict__ Hout, float* __restrict__ colsum,
        float* __restrict__ colsumsq) {
    __shared__ float ls[256], lq[256];
    int t = threadIdx.x;
    int c = t & 127, half = t >> 7;
    int rbase = blockIdx.x * 64;
    float sum = 0.f, sq = 0.f;
    #pragma unroll 4
    for (int i = 0; i < 32; ++i) {
        int r = rbase + half + i * 2;
        float v = Hout[(size_t)r * HD + c];
        sum += v;
        sq += v * v;
    }
    ls[t] = sum;
    lq[t] = sq;
    __syncthreads();
    if (t < 128) {
        sum = ls[t] + ls[t + 128];
        sq = lq[t] + lq[t + 128];
        atomicAdd(colsum + c, sum);
        atomicAdd(colsumsq + c, sq);
    }
}

// K5: out = tanh((h - mean) * rstd * gamma + beta), in place; fast tanh
__global__ __launch_bounds__(256) void k_apply(
        float* __restrict__ Hout, const float* __restrict__ colsum,
        const float* __restrict__ colsumsq, const float* __restrict__ gamma,
        const float* __restrict__ beta) {
    int idx = blockIdx.x * 256 + threadIdx.x;  // float4 index
    if (idx >= N_NODES * HD / 4) return;
    int c0 = (idx * 4) & 127;
    float4 hv4 = ((const float4*)Hout)[idx];
    const float inv = 1.f / (float)N_NODES;
    float hv[4] = {hv4.x, hv4.y, hv4.z, hv4.w};
    float o[4];
    #pragma unroll
    for (int j = 0; j < 4; ++j) {
        int c = c0 + j;
        float mean = colsum[c] * inv;
        float var = colsumsq[c] * inv - mean * mean;
        float rstd = rsqrtf(var + BN_EPS);
        float x = (hv[j] - mean) * rstd * gamma[c] + beta[c];
        o[j] = 1.f - 2.f / (__expf(2.f * x) + 1.f);
    }
    ((float4*)Hout)[idx] = make_float4(o[0], o[1], o[2], o[3]);
}

extern "C" void kernel_launch(void* const* d_in, const int* in_sizes, int n_in,
                              void* d_out, int out_size, void* d_ws, size_t ws_size,
                              hipStream_t stream) {
    const float* ent_emb  = (const float*)d_in[0];
    const float* rel_emb  = (const float*)d_in[1];
    const float* neigh_w  = (const float*)d_in[2];
    const float* bn_gamma = (const float*)d_in[3];
    const float* bn_beta  = (const float*)d_in[4];
    const int*   rel_id   = (const int*)d_in[5];
    const int*   dst      = (const int*)d_in[6];
    float* out = (float*)d_out;

    // workspace layout (4-byte words)
    unsigned* cnt4   = (unsigned*)d_ws;                       // [40000*60]
    float*    colsum = (float*)d_ws + 2400000;                // [128]
    float*    colsumsq = colsum + 128;                        // [128]
    _Float16* R_hl   = (_Float16*)((float*)d_ws + 2400256);   // [480*256] halfs
    _Float16* RWT    = (_Float16*)((float*)d_ws + 2461696);   // [128*960] halfs
    // total 2,523,136 words (~10.1 MB); only cnt4+colsums need zeroing

    hipMemsetAsync(d_ws, 0, (size_t)2400256 * 4, stream);

    k_cnt<<<(N_EDGES + 255) / 256, 256, 0, stream>>>(dst, rel_id, cnt4);
    k_rw<<<480, 128, 0, stream>>>(rel_emb, neigh_w, R_hl, RWT);
    k_mega<<<N_NODES / 32, 256, 0, stream>>>(ent_emb, R_hl, RWT, cnt4, out);
    k_stats<<<N_NODES / 64, 256, 0, stream>>>(out, colsum, colsumsq);
    k_apply<<<N_NODES * HD / 4 / 256, 256, 0, stream>>>(out, colsum, colsumsq, bn_gamma, bn_beta);
}

// Round 15
// 176.296 us; speedup vs baseline: 1.3365x; 1.2718x over previous
//
#include <hip/hip_runtime.h>

#define N_NODES 40000
#define N_EDGES 640000
#define HD 128
#define N_REL2 474
#define BN_EPS 1e-5f

typedef _Float16 half8 __attribute__((ext_vector_type(8)));
typedef float f32x4 __attribute__((ext_vector_type(4)));

// K1: transposed nibble counts: block of 32 nodes; word = [(node>>5)*480 + rel]*4 + ((node&31)>>3)
__global__ __launch_bounds__(256) void k_cnt(
        const int* __restrict__ dst, const int* __restrict__ rel_id,
        unsigned* __restrict__ cntT) {
    int e = blockIdx.x * 256 + threadIdx.x;
    if (e < N_EDGES) {
        int d = dst[e], r = rel_id[e];
        int nb = d >> 5, lrow = d & 31;
        atomicAdd(&cntT[(size_t)(nb * 480 + r) * 4 + (lrow >> 3)], 1u << ((lrow & 7) * 4));
    }
}

// K2: R_hl = fp16 hi|lo of rel_emb ([480][256], pad rows zero);
//     RWT = (rel_emb @ neigh_w)^T fp16 hi|lo ([128][960]: hi 480 | lo 480)
__global__ __launch_bounds__(128) void k_rw(
        const float* __restrict__ R, const float* __restrict__ W,
        _Float16* __restrict__ R_hl, _Float16* __restrict__ RWT) {
    __shared__ float row[HD];
    int r = blockIdx.x, c = threadIdx.x;
    float rv = (r < N_REL2) ? R[(size_t)r * HD + c] : 0.f;
    row[c] = rv;
    _Float16 hh = (_Float16)rv;
    R_hl[r * 256 + c] = hh;
    R_hl[r * 256 + 128 + c] = (_Float16)(rv - (float)hh);
    __syncthreads();
    float acc = 0.f;
    #pragma unroll 8
    for (int k = 0; k < HD; ++k) acc += row[k] * W[(size_t)k * HD + c];
    _Float16 ah = (_Float16)acc;
    RWT[c * 960 + r] = ah;
    RWT[c * 960 + 480 + r] = (_Float16)(acc - (float)ah);
}

// K3 (fat): 32 nodes/block. wave = (rh row-half, ch col-half); each wave owns
// 16 FULL rows for its 240-col half -> wave-local masked softmax.
// GEMM1 (3-term hi/lo) -> masked max -> As fp16 (LDS) -> GEMM2 (2-term) -> h.
__global__ __launch_bounds__(256) void k_fat(
        const float* __restrict__ ent, const _Float16* __restrict__ R_hl,
        const _Float16* __restrict__ RWT, const unsigned* __restrict__ cntT,
        float* __restrict__ h) {
    __shared__ __align__(16) unsigned char lds[79872];
    _Float16* As  = (_Float16*)lds;               // [32][488] halfs (31232 B)
    unsigned* cl  = (unsigned*)(lds + 31232);     // [480][5] u32 (9600 B)
    float*    mh  = (float*)(lds + 40832);        // [2][32]
    float*    lsu = (float*)(lds + 41088);        // [2][32]
    char*     Bst = (char*)(lds + 41472);         // 38400 B: gemm1 plane / gemm2 RWT slice

    int t = threadIdx.x, w = t >> 6, l = t & 63, lr = l & 15, lk = l >> 4;
    int nb = blockIdx.x;
    int rh = w & 1, ch = w >> 1;
    int node = nb * 32 + rh * 16 + lr;

    // stage transposed cnt words (first barrier below orders it)
    const unsigned* cg = cntT + (size_t)nb * 1920;
    for (int i = t; i < 1920; i += 256)
        cl[(i >> 2) * 5 + (i & 3)] = cg[i];

    f32x4 acc[15];
    #pragma unroll
    for (int i = 0; i < 15; ++i) acc[i] = (f32x4){0.f, 0.f, 0.f, 0.f};

    // ---- GEMM1: G rows for this wave (16 rows x 240 cols), hi/lo 3-term ----
    for (int kf = 0; kf < 4; ++kf) {
        const float* ep = ent + (size_t)node * HD + kf * 32 + lk * 8;
        float4 v0 = *(const float4*)ep;
        float4 v1 = *(const float4*)(ep + 4);
        float vv[8] = {v0.x, v0.y, v0.z, v0.w, v1.x, v1.y, v1.z, v1.w};
        half8 ah, al;
        #pragma unroll
        for (int j = 0; j < 8; ++j) {
            _Float16 hh = (_Float16)vv[j];
            ah[j] = hh;
            al[j] = (_Float16)(vv[j] - (float)hh);
        }
        // pass 1: hi plane
        for (int i = t; i < 1920; i += 256) {
            int rel = i >> 2, seg = i & 3;
            *(float4*)(Bst + rel * 80 + seg * 16) =
                *(const float4*)(R_hl + (size_t)rel * 256 + kf * 32 + seg * 8);
        }
        __syncthreads();
        #pragma unroll
        for (int tl = 0; tl < 15; ++tl) {
            const char* bp = Bst + (ch * 240 + tl * 16 + lr) * 80 + lk * 16;
            half8 bh = *(const half8*)bp;
            acc[tl] = __builtin_amdgcn_mfma_f32_16x16x32_f16(ah, bh, acc[tl], 0, 0, 0);
            acc[tl] = __builtin_amdgcn_mfma_f32_16x16x32_f16(al, bh, acc[tl], 0, 0, 0);
        }
        __syncthreads();
        // pass 2: lo plane
        for (int i = t; i < 1920; i += 256) {
            int rel = i >> 2, seg = i & 3;
            *(float4*)(Bst + rel * 80 + seg * 16) =
                *(const float4*)(R_hl + (size_t)rel * 256 + 128 + kf * 32 + seg * 8);
        }
        __syncthreads();
        #pragma unroll
        for (int tl = 0; tl < 15; ++tl) {
            const char* bp = Bst + (ch * 240 + tl * 16 + lr) * 80 + lk * 16;
            half8 bl = *(const half8*)bp;
            acc[tl] = __builtin_amdgcn_mfma_f32_16x16x32_f16(ah, bl, acc[tl], 0, 0, 0);
        }
        __syncthreads();
    }

    // ---- mask words: ONE u32 per (lane, tile) covers all 4 regs ----
    unsigned cw[15];
    int cwsel = rh * 2 + (lk >> 1);
    #pragma unroll
    for (int tl = 0; tl < 15; ++tl)
        cw[tl] = cl[(ch * 240 + tl * 16 + lr) * 5 + cwsel];

    // ---- masked row max (wave-local + one cross-ch combine) ----
    float m[4];
    #pragma unroll
    for (int reg = 0; reg < 4; ++reg) {
        int shift = ((lk & 1) * 4 + reg) * 4;
        float mm = -INFINITY;
        #pragma unroll
        for (int tl = 0; tl < 15; ++tl)
            if ((cw[tl] >> shift) & 15u) mm = fmaxf(mm, acc[tl][reg]);
        #pragma unroll
        for (int msk = 1; msk <= 8; msk <<= 1)
            mm = fmaxf(mm, __shfl_xor(mm, msk, 64));
        if (lr == 0) mh[ch * 32 + rh * 16 + lk * 4 + reg] = mm;
        m[reg] = mm;
    }
    __syncthreads();
    #pragma unroll
    for (int reg = 0; reg < 4; ++reg) {
        int row = rh * 16 + lk * 4 + reg;
        m[reg] = fmaxf(mh[row], mh[32 + row]);
    }

    // ---- A = cnt * exp(G - m) -> LDS fp16; wave-local row sums ----
    float ps[4] = {0.f, 0.f, 0.f, 0.f};
    #pragma unroll
    for (int tl = 0; tl < 15; ++tl) {
        int col = ch * 240 + tl * 16 + lr;
        #pragma unroll
        for (int reg = 0; reg < 4; ++reg) {
            int shift = ((lk & 1) * 4 + reg) * 4;
            unsigned nib = (cw[tl] >> shift) & 15u;
            float a = 0.f;
            if (nib) a = (float)nib * __expf(acc[tl][reg] - m[reg]);
            ps[reg] += a;
            As[(rh * 16 + lk * 4 + reg) * 488 + col] = (_Float16)a;
        }
    }
    #pragma unroll
    for (int reg = 0; reg < 4; ++reg) {
        #pragma unroll
        for (int msk = 1; msk <= 8; msk <<= 1)
            ps[reg] += __shfl_xor(ps[reg], msk, 64);
        if (lr == 0) lsu[ch * 32 + rh * 16 + lk * 4 + reg] = ps[reg];
    }
    __syncthreads();

    // ---- GEMM2: h = As(32x480) @ RW(480x128); RWT slice staged per K-step ----
    int rh2 = w & 1, ch2 = w >> 1;
    f32x4 a2[4];
    #pragma unroll
    for (int i = 0; i < 4; ++i) a2[i] = (f32x4){0.f, 0.f, 0.f, 0.f};
    for (int kf2 = 0; kf2 < 15; ++kf2) {
        for (int i = t; i < 1024; i += 256) {
            int plane = i >> 9, j = i & 511, col = j >> 2, seg = j & 3;
            *(float4*)(Bst + plane * 10240 + col * 80 + seg * 16) =
                *(const float4*)(RWT + (size_t)col * 960 + plane * 480 + kf2 * 32 + seg * 8);
        }
        __syncthreads();
        half8 af = *(const half8*)((const char*)As + (rh2 * 16 + lr) * 976 + kf2 * 64 + lk * 16);
        #pragma unroll
        for (int t2 = 0; t2 < 4; ++t2) {
            const char* bp = Bst + (ch2 * 64 + t2 * 16 + lr) * 80 + lk * 16;
            half8 bh = *(const half8*)bp;
            half8 bl = *(const half8*)(bp + 10240);
            a2[t2] = __builtin_amdgcn_mfma_f32_16x16x32_f16(af, bh, a2[t2], 0, 0, 0);
            a2[t2] = __builtin_amdgcn_mfma_f32_16x16x32_f16(af, bl, a2[t2], 0, 0, 0);
        }
        __syncthreads();
    }

    // ---- epilogue: scale by 1/l, write h ----
    #pragma unroll
    for (int reg = 0; reg < 4; ++reg) {
        int row = rh2 * 16 + lk * 4 + reg;
        float lv = lsu[row] + lsu[32 + row];
        float invl = (lv > 0.f) ? 1.f / lv : 0.f;
        #pragma unroll
        for (int t2 = 0; t2 < 4; ++t2)
            h[((size_t)nb * 32 + row) * HD + ch2 * 64 + t2 * 16 + lr] = a2[t2][reg] * invl;
    }
}

// K4: per-column sum / sumsq over rows (block-partial -> global atomics)
__global__ __launch_bounds__(256) void k_stats(
        const float* __restrict__ Hout, float* __restrict__ colsum,
        float* __restrict__ colsumsq) {
    __shared__ float ls[256], lq[256];
    int t = threadIdx.x;
    int c = t & 127, half = t >> 7;
    int rbase = blockIdx.x * 64;
    float sum = 0.f, sq = 0.f;
    #pragma unroll 4
    for (int i = 0; i < 32; ++i) {
        int r = rbase + half + i * 2;
        float v = Hout[(size_t)r * HD + c];
        sum += v;
        sq += v * v;
    }
    ls[t] = sum;
    lq[t] = sq;
    __syncthreads();
    if (t < 128) {
        sum = ls[t] + ls[t + 128];
        sq = lq[t] + lq[t + 128];
        atomicAdd(colsum + c, sum);
        atomicAdd(colsumsq + c, sq);
    }
}

// K5: out = tanh((h - mean) * rstd * gamma + beta), in place; fast tanh
__global__ __launch_bounds__(256) void k_apply(
        float* __restrict__ Hout, const float* __restrict__ colsum,
        const float* __restrict__ colsumsq, const float* __restrict__ gamma,
        const float* __restrict__ beta) {
    int idx = blockIdx.x * 256 + threadIdx.x;  // float4 index
    if (idx >= N_NODES * HD / 4) return;
    int c0 = (idx * 4) & 127;
    float4 hv4 = ((const float4*)Hout)[idx];
    const float inv = 1.f / (float)N_NODES;
    float hv[4] = {hv4.x, hv4.y, hv4.z, hv4.w};
    float o[4];
    #pragma unroll
    for (int j = 0; j < 4; ++j) {
        int c = c0 + j;
        float mean = colsum[c] * inv;
        float var = colsumsq[c] * inv - mean * mean;
        float rstd = rsqrtf(var + BN_EPS);
        float x = (hv[j] - mean) * rstd * gamma[c] + beta[c];
        o[j] = 1.f - 2.f / (__expf(2.f * x) + 1.f);
    }
    ((float4*)Hout)[idx] = make_float4(o[0], o[1], o[2], o[3]);
}

extern "C" void kernel_launch(void* const* d_in, const int* in_sizes, int n_in,
                              void* d_out, int out_size, void* d_ws, size_t ws_size,
                              hipStream_t stream) {
    const float* ent_emb  = (const float*)d_in[0];
    const float* rel_emb  = (const float*)d_in[1];
    const float* neigh_w  = (const float*)d_in[2];
    const float* bn_gamma = (const float*)d_in[3];
    const float* bn_beta  = (const float*)d_in[4];
    const int*   rel_id   = (const int*)d_in[5];
    const int*   dst      = (const int*)d_in[6];
    float* out = (float*)d_out;

    // workspace layout (4-byte words)
    unsigned* cntT   = (unsigned*)d_ws;                       // [1250*480*4] = 2,400,000
    float*    colsum = (float*)d_ws + 2400000;                // [128]
    float*    colsumsq = colsum + 128;                        // [128]
    _Float16* R_hl   = (_Float16*)((float*)d_ws + 2400256);   // [480*256] halfs
    _Float16* RWT    = (_Float16*)((float*)d_ws + 2461696);   // [128*960] halfs
    // total 2,523,136 words (~10.1 MB)

    hipMemsetAsync(d_ws, 0, (size_t)2400256 * 4, stream);

    k_cnt<<<(N_EDGES + 255) / 256, 256, 0, stream>>>(dst, rel_id, cntT);
    k_rw<<<480, 128, 0, stream>>>(rel_emb, neigh_w, R_hl, RWT);
    k_fat<<<N_NODES / 32, 256, 0, stream>>>(ent_emb, R_hl, RWT, cntT, out);
    k_stats<<<N_NODES / 64, 256, 0, stream>>>(out, colsum, colsumsq);
    k_apply<<<N_NODES * HD / 4 / 256, 256, 0, stream>>>(out, colsum, colsumsq, bn_gamma, bn_beta);
}